// Round 7
// baseline (13099.582 us; speedup 1.0000x reference)
//
#include <hip/hip_runtime.h>

#define LAYERS 6
#define BB 10
#define TT 2048
#define II 128
#define HH 256
#define GPL 32          // blocks per layer
#define DEPTH 8         // h ring-buffer depth (power of 2)
#define NTH 256
#define NCOL 8          // h-columns per block
#define NROW 32         // gate rows per block (4 gates x 8 cols)
#define HCSTR 520       // padded LDS stride for h_cat rows
#define PSTR 392        // red p-plane stride: 392 mod 32 = 8 -> planes offset by 8 banks
#define NU64 (BB * HH / 2)   // 1280 ull per h-exchange

typedef unsigned long long u64;

struct __align__(16) Smem {
    float hc[BB][HCSTR];     // [x_t | h_below , h_own] per batch (below region persists from slack)
    float red[4][PSTR];      // 4 K-partials x 32 rows x 12-stride (NOT aliased with hc)
    float cst[NCOL][BB];
    float bias_s[NROW];
};

__device__ __forceinline__ float fsig(float x) { return 1.0f / (1.0f + __expf(-x)); }
__device__ __forceinline__ float ftanh(float x) {
    x = fminf(fmaxf(x, -15.0f), 15.0f);
    float e = __expf(2.0f * x);
    return (e - 1.0f) / (e + 1.0f);
}
__device__ __forceinline__ int ld_cnt(const int* p) {
    return __hip_atomic_load(p, __ATOMIC_RELAXED, __HIP_MEMORY_SCOPE_AGENT);
}
__device__ __forceinline__ u64 ld_u64(const u64* p) {
    return __hip_atomic_load(p, __ATOMIC_RELAXED, __HIP_MEMORY_SCOPE_AGENT);
}
__device__ __forceinline__ void st_u64(u64* p, u64 v) {
    __hip_atomic_store(p, v, __ATOMIC_RELAXED, __HIP_MEMORY_SCOPE_AGENT);
}
__device__ __forceinline__ float2 u2f(u64 v) { union { u64 u; float2 f; } c; c.u = v; return c.f; }
__device__ __forceinline__ u64 f2u(float a, float b) {
    union { float2 f; u64 u; } c; c.f = make_float2(a, b); return c.u;
}
// VALU cross-lane add: v += lane-permuted(v). 0xB1=xor1, 0x4E=xor2, 0x128=row_ror:8 (=xor8)
template <int CTRL>
__device__ __forceinline__ float dpp_xadd(float v) {
    int t = __builtin_amdgcn_mov_dpp(__float_as_int(v), CTRL, 0xf, 0xf, true);
    return v + __int_as_float(t);
}

// CH4: 4 -> K=512 (layers 1..5), 3 -> K=384 (layer 0)
template <int CH4>
__device__ void run_layer(Smem& sm, int l, int s,
                          const float* __restrict__ x,
                          const float* __restrict__ h0,
                          const float* __restrict__ c0,
                          const float* __restrict__ Wih0,
                          const float* __restrict__ Wih,
                          const float* __restrict__ Whh,
                          const float* __restrict__ bih,
                          const float* __restrict__ bhh,
                          float* __restrict__ out,
                          int* done, float* hring)
{
    constexpr int K = CH4 * 128;   // 512 or 384
    constexpr int F = K - HH;      // 256 or 128 (input-feature width)
    constexpr int XC = CH4 - 2;    // x-part chunks [0,XC); h-part [XC,CH4)
    const int tid  = threadIdx.x;
    const int kc   = tid & 31;
    const int rg   = tid >> 5;
    const int wave = tid >> 6;

    const float* WihL = (F == II) ? Wih0 : (Wih + (size_t)(l - 1) * 4 * HH * HH);
    const float* WhhL = Whh + (size_t)l * 4 * HH * HH;

    // ---- persistent weight registers: 4 rows x CH4 float4 ----
    float4 wreg[4][CH4];
    #pragma unroll
    for (int ri = 0; ri < 4; ++ri) {
        const int rloc = rg * 4 + ri;
        const int gr = (rloc >> 3) * HH + s * NCOL + (rloc & 7);
        #pragma unroll
        for (int i4 = 0; i4 < CH4; ++i4) {
            const int k0 = (i4 * 32 + kc) * 4;
            float tmp[4];
            #pragma unroll
            for (int c = 0; c < 4; ++c) {
                const int kk = k0 + c;
                tmp[c] = (kk < F) ? WihL[(size_t)gr * F + kk]
                                  : WhhL[(size_t)gr * HH + (kk - F)];
            }
            wreg[ri][i4] = make_float4(tmp[0], tmp[1], tmp[2], tmp[3]);
        }
    }
    if (tid < NROW) {
        const int gr = (tid >> 3) * HH + s * NCOL + (tid & 7);
        sm.bias_s[tid] = bih[l * 4 * HH + gr] + bhh[l * 4 * HH + gr];
    }
    if (tid < NCOL * BB) {
        const int j = tid & 7, b = tid >> 3;
        sm.cst[j][b] = c0[((size_t)l * BB + b) * HH + s * NCOL + j];
    }

    u64* const ringu = (u64*)(hring + (size_t)l * DEPTH * BB * HH);

    // ---- prologue: stage xbuf(0) into hc[.][0..F) ----
    if (F == II) {
        #pragma unroll
        for (int i = 0; i < 2; ++i) {
            const int q = tid + i * NTH;
            if (q < BB * (II / 4))
                *(float4*)&sm.hc[q >> 5][(q & 31) * 4] =
                    *(const float4*)&x[((size_t)(q >> 5) * TT + 0) * II + (q & 31) * 4];
        }
    } else {
        while (ld_cnt(&done[(l - 1) * 32]) < GPL) __builtin_amdgcn_s_sleep(2);
        const u64* src = (const u64*)(hring + (size_t)(l - 1) * DEPTH * BB * HH); // slot 0
        u64 v[5];
        #pragma unroll
        for (int i = 0; i < 5; ++i) v[i] = ld_u64(src + tid + i * NTH);
        #pragma unroll
        for (int i = 0; i < 5; ++i) {
            const int f = 2 * (tid + i * NTH);
            *(float2*)&sm.hc[f >> 8][f & 255] = u2f(v[i]);
        }
    }
    __syncthreads();

    for (int t = 0; t < TT; ++t) {
        // ---- A: x-part GEMM from xbuf (masks publish->detect propagation) ----
        float acc[4][BB];
        #pragma unroll
        for (int ri = 0; ri < 4; ++ri)
            #pragma unroll
            for (int b = 0; b < BB; ++b) acc[ri][b] = 0.0f;

        #pragma unroll
        for (int i4 = 0; i4 < XC; ++i4) {
            const int col = (i4 * 32 + kc) * 4;
            #pragma unroll
            for (int b = 0; b < BB; ++b) {
                const float4 h4 = *(const float4*)&sm.hc[b][col];
                #pragma unroll
                for (int ri = 0; ri < 4; ++ri) {
                    acc[ri][b] = fmaf(wreg[ri][i4].x, h4.x, acc[ri][b]);
                    acc[ri][b] = fmaf(wreg[ri][i4].y, h4.y, acc[ri][b]);
                    acc[ri][b] = fmaf(wreg[ri][i4].z, h4.z, acc[ri][b]);
                    acc[ri][b] = fmaf(wreg[ri][i4].w, h4.w, acc[ri][b]);
                }
            }
        }

        // ---- B: own-layer handshake — single aggregated line, every wave, no sleep ----
        if (t > 0) {
            const int tgt = GPL * t;
            while (ld_cnt(&done[l * 32]) < tgt) { }
        }

        // ---- C: own-h gather (5 x ull sc1) -> hbuf ----
        {
            const u64* src = (t == 0) ? (const u64*)(h0 + (size_t)l * BB * HH)
                                      : ringu + (size_t)((t - 1) & (DEPTH - 1)) * NU64;
            u64 v[5];
            #pragma unroll
            for (int i = 0; i < 5; ++i) v[i] = ld_u64(src + tid + i * NTH);
            #pragma unroll
            for (int i = 0; i < 5; ++i) {
                const int f = 2 * (tid + i * NTH);
                *(float2*)&sm.hc[f >> 8][F + (f & 255)] = u2f(v[i]);
            }
        }
        __syncthreads();   // B1: hbuf staged

        // ---- D: h-part GEMM (critical-path compute) ----
        #pragma unroll
        for (int i4 = XC; i4 < CH4; ++i4) {
            const int col = (i4 * 32 + kc) * 4;
            #pragma unroll
            for (int b = 0; b < BB; ++b) {
                const float4 h4 = *(const float4*)&sm.hc[b][col];
                #pragma unroll
                for (int ri = 0; ri < 4; ++ri) {
                    acc[ri][b] = fmaf(wreg[ri][i4].x, h4.x, acc[ri][b]);
                    acc[ri][b] = fmaf(wreg[ri][i4].y, h4.y, acc[ri][b]);
                    acc[ri][b] = fmaf(wreg[ri][i4].z, h4.z, acc[ri][b]);
                    acc[ri][b] = fmaf(wreg[ri][i4].w, h4.w, acc[ri][b]);
                }
            }
        }

        // ---- DPP tree-reduce over kc bits {0,1,3}: 32 -> 4 partials ----
        #pragma unroll
        for (int ri = 0; ri < 4; ++ri)
            #pragma unroll
            for (int b = 0; b < BB; ++b) {
                float v = acc[ri][b];
                v = dpp_xadd<0xB1>(v);
                v = dpp_xadd<0x4E>(v);
                v = dpp_xadd<0x128>(v);
                acc[ri][b] = v;
            }

        // ---- dump 4 surviving partials (kc in {0,4,16,20}); constant acc indices ----
        if ((kc & 0x0B) == 0) {
            const int p = ((kc >> 2) & 1) | ((kc >> 3) & 2);
            float* dst = &sm.red[p][(rg * 4) * 12];
            #pragma unroll
            for (int ri = 0; ri < 4; ++ri) {
                *(float4*)&dst[ri * 12 + 0] =
                    make_float4(acc[ri][0], acc[ri][1], acc[ri][2], acc[ri][3]);
                *(float4*)&dst[ri * 12 + 4] =
                    make_float4(acc[ri][4], acc[ri][5], acc[ri][6], acc[ri][7]);
                *(float2*)&dst[ri * 12 + 8] = make_float2(acc[ri][8], acc[ri][9]);
            }
        }
        __syncthreads();   // B2: partials visible; all hbuf/xbuf reads complete

        if (wave == 0) {
            // ---- E: gate math + state update + publish (wave 0 only; 40 paired lanes) ----
            if (tid < 40) {
                const int b = tid >> 2, j = (tid & 3) * 2;
                float cc0, cc1, hh0, hh1;
                #pragma unroll
                for (int e = 0; e < 2; ++e) {
                    const int jj = j + e;
                    float g4[4];
                    #pragma unroll
                    for (int g = 0; g < 4; ++g) {
                        const int col = (g * 8 + jj) * 12 + b;
                        g4[g] = ((sm.red[0][col] + sm.red[1][col])
                               + (sm.red[2][col] + sm.red[3][col])) + sm.bias_s[g * 8 + jj];
                    }
                    float c = sm.cst[jj][b];
                    c = fsig(g4[1]) * c + fsig(g4[0]) * ftanh(g4[2]);
                    const float h = fsig(g4[3]) * ftanh(c);
                    sm.cst[jj][b] = c;
                    if (e == 0) { cc0 = c; hh0 = h; } else { cc1 = c; hh1 = h; }
                }
                st_u64(ringu + (size_t)(t & (DEPTH - 1)) * NU64 + b * (HH / 2) + s * 4 + (tid & 3),
                       f2u(hh0, hh1));
                if (t == TT - 1)
                    *(float2*)&out[((size_t)l * BB + b) * HH + s * NCOL + j] =
                        make_float2(cc0, cc1);
            }
            if (tid == 0)   // release RMW: waits wave-0 vmcnt -> h stores are at LLC first
                __hip_atomic_fetch_add(&done[l * 32], 1, __ATOMIC_RELEASE,
                                       __HIP_MEMORY_SCOPE_AGENT);
        } else if (t + 1 < TT) {
            // ---- F: slack (waves 1-3): prefetch next-step below/x into xbuf ----
            if (wave == 3 && l < LAYERS - 1 && t >= DEPTH - 1) {
                const int tgt = GPL * (t + 2 - DEPTH);   // consumer staged slot (t+1)&7's old data
                while (ld_cnt(&done[(l + 1) * 32]) < tgt) __builtin_amdgcn_s_sleep(2);
            }
            if (F == II) {
                const int base = tid - 64;
                #pragma unroll
                for (int i = 0; i < 2; ++i) {
                    const int q = base + i * 192;
                    if (q < BB * (II / 4))
                        *(float4*)&sm.hc[q >> 5][(q & 31) * 4] =
                            *(const float4*)&x[((size_t)(q >> 5) * TT + (t + 1)) * II + (q & 31) * 4];
                }
            } else {
                const int tgt = GPL * (t + 2);           // below finished step t+1
                while (ld_cnt(&done[(l - 1) * 32]) < tgt) __builtin_amdgcn_s_sleep(2);
                const u64* src = (const u64*)(hring + (size_t)(l - 1) * DEPTH * BB * HH)
                               + (size_t)((t + 1) & (DEPTH - 1)) * NU64;
                const int base = tid - 64;
                u64 v[7];
                #pragma unroll
                for (int i = 0; i < 7; ++i) {
                    const int u = base + i * 192;
                    v[i] = (u < NU64) ? ld_u64(src + u) : 0ULL;
                }
                #pragma unroll
                for (int i = 0; i < 7; ++i) {
                    const int u = base + i * 192;
                    if (u < NU64) {
                        const int f = 2 * u;
                        *(float2*)&sm.hc[f >> 8][f & 255] = u2f(v[i]);
                    }
                }
            }
        }
        __syncthreads();   // B3: xbuf(t+1) staged; loop
    }
}

__global__ __launch_bounds__(NTH, 1)
void lstm_persistent(const float* __restrict__ x, const float* __restrict__ h0,
                     const float* __restrict__ c0, const float* __restrict__ Wih0,
                     const float* __restrict__ Wih, const float* __restrict__ Whh,
                     const float* __restrict__ bih, const float* __restrict__ bhh,
                     float* __restrict__ out, int* done, float* hring)
{
    __shared__ Smem sm;
    const int l = blockIdx.x / GPL;
    const int s = blockIdx.x % GPL;
    if (l == 0)
        run_layer<3>(sm, l, s, x, h0, c0, Wih0, Wih, Whh, bih, bhh, out, done, hring);
    else
        run_layer<4>(sm, l, s, x, h0, c0, Wih0, Wih, Whh, bih, bhh, out, done, hring);
}

extern "C" void kernel_launch(void* const* d_in, const int* in_sizes, int n_in,
                              void* d_out, int out_size, void* d_ws, size_t ws_size,
                              hipStream_t stream) {
    const float* x    = (const float*)d_in[0];
    const float* h0   = (const float*)d_in[1];
    const float* c0   = (const float*)d_in[2];
    const float* Wih0 = (const float*)d_in[3];
    const float* Wih  = (const float*)d_in[4];
    const float* Whh  = (const float*)d_in[5];
    const float* bih  = (const float*)d_in[6];
    const float* bhh  = (const float*)d_in[7];
    float* out  = (float*)d_out;

    int*   done  = (int*)d_ws;                        // per-layer aggregated counters, 128B apart
    float* hring = (float*)((char*)d_ws + 16384);     // [L][DEPTH][B][H] ring

    (void)hipMemsetAsync(d_ws, 0, 16384, stream);     // ws is poisoned 0xAA each launch
    hipLaunchKernelGGL(lstm_persistent, dim3(LAYERS * GPL), dim3(NTH), 0, stream,
                       x, h0, c0, Wih0, Wih, Whh, bih, bhh, out, done, hring);
}

// Round 8
// 10309.374 us; speedup vs baseline: 1.2706x; 1.2706x over previous
//
#include <hip/hip_runtime.h>

#define LAYERS 6
#define BB 10
#define TT 2048
#define II 128
#define HH 256
#define GPL 32          // blocks per layer
#define DEPTH 8         // h ring-buffer depth (power of 2)
#define NTH 256
#define NCOL 8          // h-columns per block
#define NROW 32         // gate rows per block (4 gates x 8 cols)
#define HCSTR 520       // padded LDS stride for h_cat rows
#define PSTR 392        // red p-plane stride: 392 mod 32 = 8 -> planes offset by 8 banks
#define NU64 (BB * HH / 2)   // 1280 ull per h-exchange

typedef unsigned long long u64;

struct __align__(16) Smem {
    float hc[BB][HCSTR];     // [x_t | h_below , h_own] per batch (below region persists from slack)
    float red[4][PSTR];      // 4 K-partials x 32 rows x 12-stride (NOT aliased with hc)
    float cst[NCOL][BB];
    float bias_s[NROW];
};

__device__ __forceinline__ float fsig(float x) { return 1.0f / (1.0f + __expf(-x)); }
__device__ __forceinline__ float ftanh(float x) {
    x = fminf(fmaxf(x, -15.0f), 15.0f);
    float e = __expf(2.0f * x);
    return (e - 1.0f) / (e + 1.0f);
}
__device__ __forceinline__ int ld_cnt(const int* p) {
    return __hip_atomic_load(p, __ATOMIC_RELAXED, __HIP_MEMORY_SCOPE_AGENT);
}
__device__ __forceinline__ u64 ld_u64(const u64* p) {
    return __hip_atomic_load(p, __ATOMIC_RELAXED, __HIP_MEMORY_SCOPE_AGENT);
}
__device__ __forceinline__ void st_u64(u64* p, u64 v) {
    __hip_atomic_store(p, v, __ATOMIC_RELAXED, __HIP_MEMORY_SCOPE_AGENT);
}
__device__ __forceinline__ float2 u2f(u64 v) { union { u64 u; float2 f; } c; c.u = v; return c.f; }
__device__ __forceinline__ u64 f2u(float a, float b) {
    union { float2 f; u64 u; } c; c.f = make_float2(a, b); return c.u;
}
// VALU cross-lane add: v += lane-permuted(v). 0xB1=xor1, 0x4E=xor2, 0x128=row_ror:8 (=xor8)
template <int CTRL>
__device__ __forceinline__ float dpp_xadd(float v) {
    int t = __builtin_amdgcn_mov_dpp(__float_as_int(v), CTRL, 0xf, 0xf, true);
    return v + __int_as_float(t);
}
// Wait until all 32 flags of a layer reach tgt. One 32-lane load of a single
// 128B line per iteration; relaxed loads; compiler barrier on exit (no cache maint).
__device__ __forceinline__ void poll32(const int* base, int tgt, bool sleep) {
    const int lane = threadIdx.x & 63;
    const int* p = base + (lane & 31);
    for (;;) {
        int v = ld_cnt(p);
        if (__ballot((lane < 32) && (v < tgt)) == 0) break;
        if (sleep) __builtin_amdgcn_s_sleep(2);
    }
    asm volatile("" ::: "memory");
}

// CH4: 4 -> K=512 (layers 1..5), 3 -> K=384 (layer 0)
template <int CH4>
__device__ void run_layer(Smem& sm, int l, int s,
                          const float* __restrict__ x,
                          const float* __restrict__ h0,
                          const float* __restrict__ c0,
                          const float* __restrict__ Wih0,
                          const float* __restrict__ Wih,
                          const float* __restrict__ Whh,
                          const float* __restrict__ bih,
                          const float* __restrict__ bhh,
                          float* __restrict__ out,
                          int* flags, float* hring)
{
    constexpr int K = CH4 * 128;   // 512 or 384
    constexpr int F = K - HH;      // 256 or 128 (input-feature width)
    constexpr int XC = CH4 - 2;    // x-part chunks [0,XC); h-part [XC,CH4)
    const int tid  = threadIdx.x;
    const int kc   = tid & 31;
    const int rg   = tid >> 5;
    const int wave = tid >> 6;

    const float* WihL = (F == II) ? Wih0 : (Wih + (size_t)(l - 1) * 4 * HH * HH);
    const float* WhhL = Whh + (size_t)l * 4 * HH * HH;

    // ---- persistent weight registers: 4 rows x CH4 float4 ----
    float4 wreg[4][CH4];
    #pragma unroll
    for (int ri = 0; ri < 4; ++ri) {
        const int rloc = rg * 4 + ri;
        const int gr = (rloc >> 3) * HH + s * NCOL + (rloc & 7);
        #pragma unroll
        for (int i4 = 0; i4 < CH4; ++i4) {
            const int k0 = (i4 * 32 + kc) * 4;
            float tmp[4];
            #pragma unroll
            for (int c = 0; c < 4; ++c) {
                const int kk = k0 + c;
                tmp[c] = (kk < F) ? WihL[(size_t)gr * F + kk]
                                  : WhhL[(size_t)gr * HH + (kk - F)];
            }
            wreg[ri][i4] = make_float4(tmp[0], tmp[1], tmp[2], tmp[3]);
        }
    }
    if (tid < NROW) {
        const int gr = (tid >> 3) * HH + s * NCOL + (tid & 7);
        sm.bias_s[tid] = bih[l * 4 * HH + gr] + bhh[l * 4 * HH + gr];
    }
    if (tid < NCOL * BB) {
        const int j = tid & 7, b = tid >> 3;
        sm.cst[j][b] = c0[((size_t)l * BB + b) * HH + s * NCOL + j];
    }

    u64* const ringu = (u64*)(hring + (size_t)l * DEPTH * BB * HH);

    // ---- prologue: stage xbuf(0) into hc[.][0..F) ----
    if (F == II) {
        #pragma unroll
        for (int i = 0; i < 2; ++i) {
            const int q = tid + i * NTH;
            if (q < BB * (II / 4))
                *(float4*)&sm.hc[q >> 5][(q & 31) * 4] =
                    *(const float4*)&x[((size_t)(q >> 5) * TT + 0) * II + (q & 31) * 4];
        }
    } else {
        poll32(flags + (l - 1) * 32, 1, true);
        const u64* src = (const u64*)(hring + (size_t)(l - 1) * DEPTH * BB * HH); // slot 0
        u64 v[5];
        #pragma unroll
        for (int i = 0; i < 5; ++i) v[i] = ld_u64(src + tid + i * NTH);
        #pragma unroll
        for (int i = 0; i < 5; ++i) {
            const int f = 2 * (tid + i * NTH);
            *(float2*)&sm.hc[f >> 8][f & 255] = u2f(v[i]);
        }
    }
    __syncthreads();

    for (int t = 0; t < TT; ++t) {
        // ---- A: x-part GEMM from xbuf (masks publish->detect propagation) ----
        float acc[4][BB];
        #pragma unroll
        for (int ri = 0; ri < 4; ++ri)
            #pragma unroll
            for (int b = 0; b < BB; ++b) acc[ri][b] = 0.0f;

        #pragma unroll
        for (int i4 = 0; i4 < XC; ++i4) {
            const int col = (i4 * 32 + kc) * 4;
            #pragma unroll
            for (int b = 0; b < BB; ++b) {
                const float4 h4 = *(const float4*)&sm.hc[b][col];
                #pragma unroll
                for (int ri = 0; ri < 4; ++ri) {
                    acc[ri][b] = fmaf(wreg[ri][i4].x, h4.x, acc[ri][b]);
                    acc[ri][b] = fmaf(wreg[ri][i4].y, h4.y, acc[ri][b]);
                    acc[ri][b] = fmaf(wreg[ri][i4].z, h4.z, acc[ri][b]);
                    acc[ri][b] = fmaf(wreg[ri][i4].w, h4.w, acc[ri][b]);
                }
            }
        }

        // ---- B: own-layer handshake (all waves; busy poll, min detect latency) ----
        if (t > 0) poll32(flags + l * 32, t, false);

        // ---- C: own-h gather (5 x ull sc1) -> hbuf ----
        {
            const u64* src = (t == 0) ? (const u64*)(h0 + (size_t)l * BB * HH)
                                      : ringu + (size_t)((t - 1) & (DEPTH - 1)) * NU64;
            u64 v[5];
            #pragma unroll
            for (int i = 0; i < 5; ++i) v[i] = ld_u64(src + tid + i * NTH);
            #pragma unroll
            for (int i = 0; i < 5; ++i) {
                const int f = 2 * (tid + i * NTH);
                *(float2*)&sm.hc[f >> 8][F + (f & 255)] = u2f(v[i]);
            }
        }
        __syncthreads();   // B1: hbuf staged

        // ---- D: h-part GEMM (critical-path compute) ----
        #pragma unroll
        for (int i4 = XC; i4 < CH4; ++i4) {
            const int col = (i4 * 32 + kc) * 4;
            #pragma unroll
            for (int b = 0; b < BB; ++b) {
                const float4 h4 = *(const float4*)&sm.hc[b][col];
                #pragma unroll
                for (int ri = 0; ri < 4; ++ri) {
                    acc[ri][b] = fmaf(wreg[ri][i4].x, h4.x, acc[ri][b]);
                    acc[ri][b] = fmaf(wreg[ri][i4].y, h4.y, acc[ri][b]);
                    acc[ri][b] = fmaf(wreg[ri][i4].z, h4.z, acc[ri][b]);
                    acc[ri][b] = fmaf(wreg[ri][i4].w, h4.w, acc[ri][b]);
                }
            }
        }

        // ---- DPP tree-reduce over kc bits {0,1,3}: 32 -> 4 partials ----
        #pragma unroll
        for (int ri = 0; ri < 4; ++ri)
            #pragma unroll
            for (int b = 0; b < BB; ++b) {
                float v = acc[ri][b];
                v = dpp_xadd<0xB1>(v);
                v = dpp_xadd<0x4E>(v);
                v = dpp_xadd<0x128>(v);
                acc[ri][b] = v;
            }

        // ---- dump 4 surviving partials (kc in {0,4,16,20}); constant acc indices ----
        if ((kc & 0x0B) == 0) {
            const int p = ((kc >> 2) & 1) | ((kc >> 3) & 2);
            float* dst = &sm.red[p][(rg * 4) * 12];
            #pragma unroll
            for (int ri = 0; ri < 4; ++ri) {
                *(float4*)&dst[ri * 12 + 0] =
                    make_float4(acc[ri][0], acc[ri][1], acc[ri][2], acc[ri][3]);
                *(float4*)&dst[ri * 12 + 4] =
                    make_float4(acc[ri][4], acc[ri][5], acc[ri][6], acc[ri][7]);
                *(float2*)&dst[ri * 12 + 8] = make_float2(acc[ri][8], acc[ri][9]);
            }
        }
        __syncthreads();   // B2: partials visible; all hbuf/xbuf reads complete

        if (wave == 0) {
            // ---- E: gate math + state update + publish (wave 0 only; 40 paired lanes) ----
            if (tid < 40) {
                const int b = tid >> 2, j = (tid & 3) * 2;
                float cc0, cc1, hh0, hh1;
                #pragma unroll
                for (int e = 0; e < 2; ++e) {
                    const int jj = j + e;
                    float g4[4];
                    #pragma unroll
                    for (int g = 0; g < 4; ++g) {
                        const int col = (g * 8 + jj) * 12 + b;
                        g4[g] = ((sm.red[0][col] + sm.red[1][col])
                               + (sm.red[2][col] + sm.red[3][col])) + sm.bias_s[g * 8 + jj];
                    }
                    float c = sm.cst[jj][b];
                    c = fsig(g4[1]) * c + fsig(g4[0]) * ftanh(g4[2]);
                    const float h = fsig(g4[3]) * ftanh(c);
                    sm.cst[jj][b] = c;
                    if (e == 0) { cc0 = c; hh0 = h; } else { cc1 = c; hh1 = h; }
                }
                st_u64(ringu + (size_t)(t & (DEPTH - 1)) * NU64 + b * (HH / 2) + s * 4 + (tid & 3),
                       f2u(hh0, hh1));
                if (t == TT - 1)
                    *(float2*)&out[((size_t)l * BB + b) * HH + s * NCOL + j] =
                        make_float2(cc0, cc1);
            }
            // manual release: drain wave-0's sc1 h-stores to the LLC, THEN relaxed flag store.
            // No buffer_wbl2 / buffer_inv anywhere on the steady-state path.
            asm volatile("s_waitcnt vmcnt(0)" ::: "memory");
            if (tid == 0)
                __hip_atomic_store(&flags[l * 32 + s], t + 1,
                                   __ATOMIC_RELAXED, __HIP_MEMORY_SCOPE_AGENT);
        } else if (t + 1 < TT) {
            // ---- F: slack (waves 1-3): prefetch next-step below/x into xbuf ----
            if (wave == 3 && l < LAYERS - 1 && t >= DEPTH - 1)
                poll32(flags + (l + 1) * 32, t + 2 - DEPTH, true);   // ring back-pressure
            if (F == II) {
                const int base = tid - 64;
                #pragma unroll
                for (int i = 0; i < 2; ++i) {
                    const int q = base + i * 192;
                    if (q < BB * (II / 4))
                        *(float4*)&sm.hc[q >> 5][(q & 31) * 4] =
                            *(const float4*)&x[((size_t)(q >> 5) * TT + (t + 1)) * II + (q & 31) * 4];
                }
            } else {
                poll32(flags + (l - 1) * 32, t + 2, true);           // below finished step t+1
                const u64* src = (const u64*)(hring + (size_t)(l - 1) * DEPTH * BB * HH)
                               + (size_t)((t + 1) & (DEPTH - 1)) * NU64;
                const int base = tid - 64;
                u64 v[7];
                #pragma unroll
                for (int i = 0; i < 7; ++i) {
                    const int u = base + i * 192;
                    v[i] = (u < NU64) ? ld_u64(src + u) : 0ULL;
                }
                #pragma unroll
                for (int i = 0; i < 7; ++i) {
                    const int u = base + i * 192;
                    if (u < NU64) {
                        const int f = 2 * u;
                        *(float2*)&sm.hc[f >> 8][f & 255] = u2f(v[i]);
                    }
                }
            }
        }
        __syncthreads();   // B3: xbuf(t+1) staged; loop
    }
}

__global__ __launch_bounds__(NTH, 1)
void lstm_persistent(const float* __restrict__ x, const float* __restrict__ h0,
                     const float* __restrict__ c0, const float* __restrict__ Wih0,
                     const float* __restrict__ Wih, const float* __restrict__ Whh,
                     const float* __restrict__ bih, const float* __restrict__ bhh,
                     float* __restrict__ out, int* flags, float* hring)
{
    __shared__ Smem sm;
    const int l = blockIdx.x / GPL;
    const int s = blockIdx.x % GPL;
    if (l == 0)
        run_layer<3>(sm, l, s, x, h0, c0, Wih0, Wih, Whh, bih, bhh, out, flags, hring);
    else
        run_layer<4>(sm, l, s, x, h0, c0, Wih0, Wih, Whh, bih, bhh, out, flags, hring);
}

extern "C" void kernel_launch(void* const* d_in, const int* in_sizes, int n_in,
                              void* d_out, int out_size, void* d_ws, size_t ws_size,
                              hipStream_t stream) {
    const float* x    = (const float*)d_in[0];
    const float* h0   = (const float*)d_in[1];
    const float* c0   = (const float*)d_in[2];
    const float* Wih0 = (const float*)d_in[3];
    const float* Wih  = (const float*)d_in[4];
    const float* Whh  = (const float*)d_in[5];
    const float* bih  = (const float*)d_in[6];
    const float* bhh  = (const float*)d_in[7];
    float* out  = (float*)d_out;

    int*   flags = (int*)d_ws;                        // [L][32] ints: one 128B line per layer
    float* hring = (float*)((char*)d_ws + 16384);     // [L][DEPTH][B][H] ring

    (void)hipMemsetAsync(d_ws, 0, 16384, stream);     // ws is poisoned 0xAA each launch
    hipLaunchKernelGGL(lstm_persistent, dim3(LAYERS * GPL), dim3(NTH), 0, stream,
                       x, h0, c0, Wih0, Wih, Whh, bih, bhh, out, flags, hring);
}

// Round 9
// 7792.892 us; speedup vs baseline: 1.6810x; 1.3229x over previous
//
#include <hip/hip_runtime.h>

#define LAYERS 6
#define BB 10
#define TT 2048
#define II 128
#define HH 256
#define GPL 32            // blocks per layer
#define DEPTH 8           // h ring-buffer depth (power of 2)
#define NTH 256
#define NROW 32           // gate rows per block (4 gates x 8 cols)
#define HCSTR 520         // padded LDS stride for h_cat rows
#define PSTR 392          // red p-plane stride (banks offset by 8 per plane)
#define SLOTU 1280        // u64 per layer-slot: 32 blocks x 40 tagged u64
#define NCOL 8

typedef unsigned long long u64;
typedef unsigned int u32;

struct __align__(16) Smem {
    float hc[BB][HCSTR];     // [x_t | h_below , h_own] per batch
    float red[4][PSTR];      // 4 K-partials x 32 rows x 12-stride
    float cst[NCOL][BB];
    float bias_s[NROW];
};

__device__ __forceinline__ float fsig(float x) { return 1.0f / (1.0f + __expf(-x)); }
__device__ __forceinline__ float ftanh(float x) {
    x = fminf(fmaxf(x, -15.0f), 15.0f);
    float e = __expf(2.0f * x);
    return (e - 1.0f) / (e + 1.0f);
}
__device__ __forceinline__ int ld_cnt(const int* p) {
    return __hip_atomic_load(p, __ATOMIC_RELAXED, __HIP_MEMORY_SCOPE_AGENT);
}
__device__ __forceinline__ void st_cnt(int* p, int v) {
    __hip_atomic_store(p, v, __ATOMIC_RELAXED, __HIP_MEMORY_SCOPE_AGENT);
}
__device__ __forceinline__ u64 ld_u64(const u64* p) {
    return __hip_atomic_load(p, __ATOMIC_RELAXED, __HIP_MEMORY_SCOPE_AGENT);
}
__device__ __forceinline__ void st_u64(u64* p, u64 v) {
    __hip_atomic_store(p, v, __ATOMIC_RELAXED, __HIP_MEMORY_SCOPE_AGENT);
}
__device__ __forceinline__ u32 bf16r(float v) {           // RNE float->bf16 bits
    u32 x = __float_as_uint(v);
    return (x + 0x7FFFu + ((x >> 16) & 1u)) >> 16;
}
__device__ __forceinline__ u64 packh(float h0, float h1, u32 tag) {
    return ((u64)tag << 32) | ((u64)bf16r(h0) << 16) | (u64)bf16r(h1);
}
__device__ __forceinline__ float2 unpackh(u64 v) {
    return make_float2(__uint_as_float(((u32)(v >> 16) & 0xFFFFu) << 16),
                       __uint_as_float(((u32)v & 0xFFFFu) << 16));
}
// u/40 exact for u < 262144
__device__ __forceinline__ int div40(int u) { return (int)(((unsigned)u * 52429u) >> 21); }

template <int CTRL>
__device__ __forceinline__ float dpp_xadd(float v) {
    int t = __builtin_amdgcn_mov_dpp(__float_as_int(v), CTRL, 0xf, 0xf, true);
    return v + __int_as_float(t);
}
// back-pressure poll: all 32 ints on one 128B line >= tgt
__device__ __forceinline__ void poll32(const int* base, int tgt, bool sleep) {
    const int lane = threadIdx.x & 63;
    const int* p = base + (lane & 31);
    for (;;) {
        int v = ld_cnt(p);
        if (__ballot((lane < 32) && (v < tgt)) == 0) break;
        if (sleep) __builtin_amdgcn_s_sleep(2);
    }
    asm volatile("" ::: "memory");
}

// CH4: 4 -> K=512 (layers 1..5), 3 -> K=384 (layer 0)
template <int CH4>
__device__ void run_layer(Smem& sm, int l, int s,
                          const float* __restrict__ x,
                          const float* __restrict__ h0,
                          const float* __restrict__ c0,
                          const float* __restrict__ Wih0,
                          const float* __restrict__ Wih,
                          const float* __restrict__ Whh,
                          const float* __restrict__ bih,
                          const float* __restrict__ bhh,
                          float* __restrict__ out,
                          int* flags, float* hring)
{
    constexpr int K = CH4 * 128;
    constexpr int F = K - HH;      // 256 or 128
    constexpr int XC = CH4 - 2;    // x-part chunks [0,XC); h-part [XC,CH4)
    const int tid  = threadIdx.x;
    const int kc   = tid & 31;
    const int rg   = tid >> 5;
    const int wave = tid >> 6;

    const float* WihL = (F == II) ? Wih0 : (Wih + (size_t)(l - 1) * 4 * HH * HH);
    const float* WhhL = Whh + (size_t)l * 4 * HH * HH;

    float4 wreg[4][CH4];
    #pragma unroll
    for (int ri = 0; ri < 4; ++ri) {
        const int rloc = rg * 4 + ri;
        const int gr = (rloc >> 3) * HH + s * NCOL + (rloc & 7);
        #pragma unroll
        for (int i4 = 0; i4 < CH4; ++i4) {
            const int k0 = (i4 * 32 + kc) * 4;
            float tmp[4];
            #pragma unroll
            for (int c = 0; c < 4; ++c) {
                const int kk = k0 + c;
                tmp[c] = (kk < F) ? WihL[(size_t)gr * F + kk]
                                  : WhhL[(size_t)gr * HH + (kk - F)];
            }
            wreg[ri][i4] = make_float4(tmp[0], tmp[1], tmp[2], tmp[3]);
        }
    }
    if (tid < NROW) {
        const int gr = (tid >> 3) * HH + s * NCOL + (tid & 7);
        sm.bias_s[tid] = bih[l * 4 * HH + gr] + bhh[l * 4 * HH + gr];
    }
    if (tid < NCOL * BB) {
        const int j = tid & 7, b = tid >> 3;
        sm.cst[j][b] = c0[((size_t)l * BB + b) * HH + s * NCOL + j];
    }

    u64* const ringu  = (u64*)(hring + (size_t)l * DEPTH * BB * HH);        // own layer slots
    const u64* belowu = (const u64*)(hring + (size_t)(l - 1) * DEPTH * BB * HH);

    // ---- prologue: stage below(0)/x(0) into hc lower ----
    if (F == II) {
        #pragma unroll
        for (int i = 0; i < 2; ++i) {
            const int q = tid + i * NTH;
            if (q < BB * (II / 4))
                *(float4*)&sm.hc[q >> 5][(q & 31) * 4] =
                    *(const float4*)&x[((size_t)(q >> 5) * TT + 0) * II + (q & 31) * 4];
        }
    } else {
        u64 v[5];
        #pragma unroll
        for (int i = 0; i < 5; ++i) v[i] = ld_u64(belowu + tid + i * NTH);
        for (;;) {
            bool bad = false;
            #pragma unroll
            for (int i = 0; i < 5; ++i) bad |= ((u32)(v[i] >> 32) != 1u);
            if (__ballot(bad) == 0) break;
            __builtin_amdgcn_s_sleep(2);
            #pragma unroll
            for (int i = 0; i < 5; ++i) v[i] = ld_u64(belowu + tid + i * NTH);
        }
        asm volatile("" ::: "memory");
        #pragma unroll
        for (int i = 0; i < 5; ++i) {
            const int u = tid + i * NTH, sp = div40(u), q = u - 40 * sp;
            *(float2*)&sm.hc[q >> 2][sp * 8 + (q & 3) * 2] = unpackh(v[i]);
        }
    }
    __syncthreads();

    u64 pk = 0;   // wave0 lanes<40: packed h of previous step, published at next A0

    for (int t = 0; t < TT; ++t) {
        // ---- A0: publish h(t-1) (tagged t) — fire-and-forget, flies during x-GEMM ----
        if (t > 0 && tid < 40)
            st_u64(ringu + (size_t)((t - 1) & (DEPTH - 1)) * SLOTU + s * 40 + tid, pk);
        // consumer progress flag (off critical path): below(t) staged during step t-1
        if (F != II && t > 0 && tid == 64) st_cnt(&flags[l * 32 + s], t);

        // ---- C-issue: own-layer tagged gather, loads in flight under x-GEMM ----
        u64 cv[5];
        const u64* ownslot = ringu + (size_t)((t - 1) & (DEPTH - 1)) * SLOTU;
        if (t > 0) {
            #pragma unroll
            for (int i = 0; i < 5; ++i) cv[i] = ld_u64(ownslot + tid + i * NTH);
        }

        // ---- A: x-part GEMM from xbuf (staged last step) ----
        float acc[4][BB];
        #pragma unroll
        for (int ri = 0; ri < 4; ++ri)
            #pragma unroll
            for (int b = 0; b < BB; ++b) acc[ri][b] = 0.0f;

        #pragma unroll
        for (int i4 = 0; i4 < XC; ++i4) {
            const int col = (i4 * 32 + kc) * 4;
            #pragma unroll
            for (int b = 0; b < BB; ++b) {
                const float4 h4 = *(const float4*)&sm.hc[b][col];
                #pragma unroll
                for (int ri = 0; ri < 4; ++ri) {
                    acc[ri][b] = fmaf(wreg[ri][i4].x, h4.x, acc[ri][b]);
                    acc[ri][b] = fmaf(wreg[ri][i4].y, h4.y, acc[ri][b]);
                    acc[ri][b] = fmaf(wreg[ri][i4].z, h4.z, acc[ri][b]);
                    acc[ri][b] = fmaf(wreg[ri][i4].w, h4.w, acc[ri][b]);
                }
            }
        }

        // ---- C-complete: tag-check (single round trip: data IS the signal) ----
        if (t > 0) {
            const u32 tg = (u32)t;
            for (;;) {
                bool bad = false;
                #pragma unroll
                for (int i = 0; i < 5; ++i) bad |= ((u32)(cv[i] >> 32) != tg);
                if (__ballot(bad) == 0) break;
                #pragma unroll
                for (int i = 0; i < 5; ++i) cv[i] = ld_u64(ownslot + tid + i * NTH);
            }
            asm volatile("" ::: "memory");
            #pragma unroll
            for (int i = 0; i < 5; ++i) {
                const int u = tid + i * NTH, sp = div40(u), q = u - 40 * sp;
                *(float2*)&sm.hc[q >> 2][F + sp * 8 + (q & 3) * 2] = unpackh(cv[i]);
            }
        } else {
            const u64* src = (const u64*)(h0 + (size_t)l * BB * HH);
            u64 v[5];
            #pragma unroll
            for (int i = 0; i < 5; ++i) v[i] = ld_u64(src + tid + i * NTH);
            #pragma unroll
            for (int i = 0; i < 5; ++i) {
                const int f = 2 * (tid + i * NTH);
                union { u64 u; float2 f2; } c; c.u = v[i];
                *(float2*)&sm.hc[f >> 8][F + (f & 255)] = c.f2;
            }
        }
        __syncthreads();   // B1: hbuf staged

        // ---- D: h-part GEMM ----
        #pragma unroll
        for (int i4 = XC; i4 < CH4; ++i4) {
            const int col = (i4 * 32 + kc) * 4;
            #pragma unroll
            for (int b = 0; b < BB; ++b) {
                const float4 h4 = *(const float4*)&sm.hc[b][col];
                #pragma unroll
                for (int ri = 0; ri < 4; ++ri) {
                    acc[ri][b] = fmaf(wreg[ri][i4].x, h4.x, acc[ri][b]);
                    acc[ri][b] = fmaf(wreg[ri][i4].y, h4.y, acc[ri][b]);
                    acc[ri][b] = fmaf(wreg[ri][i4].z, h4.z, acc[ri][b]);
                    acc[ri][b] = fmaf(wreg[ri][i4].w, h4.w, acc[ri][b]);
                }
            }
        }
        #pragma unroll
        for (int ri = 0; ri < 4; ++ri)
            #pragma unroll
            for (int b = 0; b < BB; ++b) {
                float v = acc[ri][b];
                v = dpp_xadd<0xB1>(v);
                v = dpp_xadd<0x4E>(v);
                v = dpp_xadd<0x128>(v);
                acc[ri][b] = v;
            }
        if ((kc & 0x0B) == 0) {
            const int p = ((kc >> 2) & 1) | ((kc >> 3) & 2);
            float* dst = &sm.red[p][(rg * 4) * 12];
            #pragma unroll
            for (int ri = 0; ri < 4; ++ri) {
                *(float4*)&dst[ri * 12 + 0] =
                    make_float4(acc[ri][0], acc[ri][1], acc[ri][2], acc[ri][3]);
                *(float4*)&dst[ri * 12 + 4] =
                    make_float4(acc[ri][4], acc[ri][5], acc[ri][6], acc[ri][7]);
                *(float2*)&dst[ri * 12 + 8] = make_float2(acc[ri][8], acc[ri][9]);
            }
        }
        __syncthreads();   // B2: partials visible

        if (wave == 0) {
            // final-step publish needs back-pressure (consumer may lag up to DEPTH-1)
            if (t == TT - 1 && l < LAYERS - 1) poll32(flags + (l + 1) * 32, TT - 8, true);
            if (tid < 40) {
                const int b = tid >> 2, j = (tid & 3) * 2;
                float cc0, cc1, hh0, hh1;
                #pragma unroll
                for (int e = 0; e < 2; ++e) {
                    const int jj = j + e;
                    float g4[4];
                    #pragma unroll
                    for (int g = 0; g < 4; ++g) {
                        const int col = (g * 8 + jj) * 12 + b;
                        g4[g] = ((sm.red[0][col] + sm.red[1][col])
                               + (sm.red[2][col] + sm.red[3][col])) + sm.bias_s[g * 8 + jj];
                    }
                    float c = sm.cst[jj][b];
                    c = fsig(g4[1]) * c + fsig(g4[0]) * ftanh(g4[2]);
                    const float h = fsig(g4[3]) * ftanh(c);
                    sm.cst[jj][b] = c;
                    if (e == 0) { cc0 = c; hh0 = h; } else { cc1 = c; hh1 = h; }
                }
                if (t == TT - 1) {
                    if (l < LAYERS - 1)
                        st_u64(ringu + (size_t)(t & (DEPTH - 1)) * SLOTU + s * 40 + tid,
                               packh(hh0, hh1, (u32)(t + 1)));
                    *(float2*)&out[((size_t)l * BB + b) * HH + s * NCOL + j] =
                        make_float2(cc0, cc1);
                } else {
                    pk = packh(hh0, hh1, (u32)(t + 1));   // published at next A0
                }
            }
        } else if (t + 1 < TT) {
            // ---- F (waves 1-3): prefetch below(t+1)/x(t+1) into xbuf ----
            if (wave == 3 && l < LAYERS - 1 && t >= 8)
                poll32(flags + (l + 1) * 32, t - 7, true);   // ring back-pressure
            if (F == II) {
                const int base = tid - 64;
                #pragma unroll
                for (int i = 0; i < 2; ++i) {
                    const int q = base + i * 192;
                    if (q < BB * (II / 4))
                        *(float4*)&sm.hc[q >> 5][(q & 31) * 4] =
                            *(const float4*)&x[((size_t)(q >> 5) * TT + (t + 1)) * II + (q & 31) * 4];
                }
            } else {
                const u64* src = belowu + (size_t)((t + 1) & (DEPTH - 1)) * SLOTU;
                const int base = tid - 64;
                const u32 tg = (u32)(t + 2);
                u64 v[7];
                #pragma unroll
                for (int i = 0; i < 7; ++i) {
                    const int u = base + i * 192;
                    v[i] = (u < SLOTU) ? ld_u64(src + u) : ((u64)tg << 32);
                }
                for (;;) {
                    bool bad = false;
                    #pragma unroll
                    for (int i = 0; i < 7; ++i) bad |= ((u32)(v[i] >> 32) != tg);
                    if (__ballot(bad) == 0) break;
                    __builtin_amdgcn_s_sleep(2);
                    #pragma unroll
                    for (int i = 0; i < 7; ++i) {
                        const int u = base + i * 192;
                        if (u < SLOTU) v[i] = ld_u64(src + u);
                    }
                }
                asm volatile("" ::: "memory");
                #pragma unroll
                for (int i = 0; i < 7; ++i) {
                    const int u = base + i * 192;
                    if (u < SLOTU) {
                        const int sp = div40(u), q = u - 40 * sp;
                        *(float2*)&sm.hc[q >> 2][sp * 8 + (q & 3) * 2] = unpackh(v[i]);
                    }
                }
            }
        }
        __syncthreads();   // B3: xbuf(t+1) + own-h LDS consistent; loop
    }
}

__global__ __launch_bounds__(NTH, 1)
void lstm_persistent(const float* __restrict__ x, const float* __restrict__ h0,
                     const float* __restrict__ c0, const float* __restrict__ Wih0,
                     const float* __restrict__ Wih, const float* __restrict__ Whh,
                     const float* __restrict__ bih, const float* __restrict__ bhh,
                     float* __restrict__ out, int* flags, float* hring)
{
    __shared__ Smem sm;
    const int l = blockIdx.x / GPL;
    const int s = blockIdx.x % GPL;
    if (l == 0)
        run_layer<3>(sm, l, s, x, h0, c0, Wih0, Wih, Whh, bih, bhh, out, flags, hring);
    else
        run_layer<4>(sm, l, s, x, h0, c0, Wih0, Wih, Whh, bih, bhh, out, flags, hring);
}

extern "C" void kernel_launch(void* const* d_in, const int* in_sizes, int n_in,
                              void* d_out, int out_size, void* d_ws, size_t ws_size,
                              hipStream_t stream) {
    const float* x    = (const float*)d_in[0];
    const float* h0   = (const float*)d_in[1];
    const float* c0   = (const float*)d_in[2];
    const float* Wih0 = (const float*)d_in[3];
    const float* Wih  = (const float*)d_in[4];
    const float* Whh  = (const float*)d_in[5];
    const float* bih  = (const float*)d_in[6];
    const float* bhh  = (const float*)d_in[7];
    float* out  = (float*)d_out;

    int*   flags = (int*)d_ws;                        // [L][32] progress ints (one line/layer)
    float* hring = (float*)((char*)d_ws + 16384);     // [L][DEPTH] tagged u64 slots (poison-safe:
                                                      // 0xAAAA.. tag never matches any t+1)
    (void)hipMemsetAsync(d_ws, 0, 16384, stream);
    hipLaunchKernelGGL(lstm_persistent, dim3(LAYERS * GPL), dim3(NTH), 0, stream,
                       x, h0, c0, Wih0, Wih, Whh, bih, bhh, out, flags, hring);
}